// Round 5
// baseline (559.509 us; speedup 1.0000x reference)
//
#include <hip/hip_runtime.h>
#include <hip/hip_bf16.h>
#include <math.h>
#include <stdint.h>

#define NB 128     // batch (images and captions)
#define NR 36      // regions
#define NW 64      // words
#define ND 1024    // dim
#define MT 48      // NR padded to 3 MFMA m-tiles
#define EPSF 1e-8f
#define LAM_SM 9.0f
#define LAM_LSE 6.0f
#define MARGINF 0.2f

typedef _Float16 f16;
typedef f16 f16x4 __attribute__((ext_vector_type(4)));
typedef f16 f16x8 __attribute__((ext_vector_type(8)));
typedef float f32x4 __attribute__((ext_vector_type(4)));

// ---------------- kernel 0: fp32 -> f16 (im zero-padded to 48 rows) + ncap --------
__global__ __launch_bounds__(256) void convert_kernel(
    const float* __restrict__ im, const float* __restrict__ s,
    f16* __restrict__ im16, f16* __restrict__ s16, float* __restrict__ ncap) {
    __shared__ float wsum[4];
    const int b = blockIdx.x, row = blockIdx.y, t = threadIdx.x;
    if (row < MT) {
        f16x4* dst = (f16x4*)(im16 + ((size_t)b * MT + row) * ND);
        if (row < NR) {
            const float4* src = (const float4*)(im + ((size_t)b * NR + row) * ND);
            float4 v = src[t];
            f16x4 h = {(f16)v.x, (f16)v.y, (f16)v.z, (f16)v.w};
            dst[t] = h;
        } else {
            dst[t] = (f16x4){(f16)0.f, (f16)0.f, (f16)0.f, (f16)0.f};
        }
    } else {
        const int w = row - MT;
        const float4* src = (const float4*)(s + ((size_t)b * NW + w) * ND);
        float4 v = src[t];
        f16x4 h = {(f16)v.x, (f16)v.y, (f16)v.z, (f16)v.w};
        ((f16x4*)(s16 + ((size_t)b * NW + w) * ND))[t] = h;
        float ss = v.x * v.x + v.y * v.y + v.z * v.z + v.w * v.w;
        #pragma unroll
        for (int off = 1; off < 64; off <<= 1) ss += __shfl_xor(ss, off, 64);
        if ((t & 63) == 0) wsum[t >> 6] = ss;
        __syncthreads();
        if (t == 0) ncap[b * NW + w] = sqrtf(wsum[0] + wsum[1] + wsum[2] + wsum[3]);
    }
}

// ---------------- kernel A: per-image f16 Gram [48][64] via MFMA ------------------
__global__ __launch_bounds__(256) void gram16_kernel(
    const f16* __restrict__ im16, f16* __restrict__ Mg16) {
    const int b = blockIdx.x, mt = blockIdx.y;          // mt 0..2
    const int wave = threadIdx.x >> 6, lane = threadIdx.x & 63;
    const int quad = lane >> 4, l16 = lane & 15;
    const int nt = wave;                                 // n-tile 0..3
    const f16* Ab = im16 + (size_t)b * (MT * ND);
    f32x4 acc = (f32x4){0.f, 0.f, 0.f, 0.f};
    for (int kk = 0; kk < ND; kk += 32) {
        f16x8 af = *(const f16x8*)(Ab + (mt * 16 + l16) * ND + kk + quad * 8);
        f16x8 bf = *(const f16x8*)(Ab + (nt * 16 + l16) * ND + kk + quad * 8);
        acc = __builtin_amdgcn_mfma_f32_16x16x32_f16(af, bf, acc, 0, 0, 0);
    }
    f16* Mb = Mg16 + (size_t)b * (MT * NW);
    #pragma unroll
    for (int r = 0; r < 4; ++r) {
        int row = mt * 16 + quad * 4 + r;
        Mb[row * NW + nt * 16 + l16] = (f16)acc[r];
    }
}

// ---------------- kernel B: block = 1 image x 4 captions (1 pair per wave) --------
// No-LDS K-loop; per-wave 8KB E^T scratch only. __launch_bounds__(256,4): cap 128
// VGPRs — R4's 2-image wave spilled (49MB scratch writes); 48-reg acc fits clean.
__global__ __launch_bounds__(256, 4) void pair_mfma_kernel(
    const f16* __restrict__ im16, const f16* __restrict__ s16,
    const int* __restrict__ s_l, const f16* __restrict__ Mg16,
    const float* __restrict__ ncap, float* __restrict__ scores) {
    __shared__ __align__(16) char smemE[4 * 8192];
    const int t = threadIdx.x;
    const int wave = t >> 6, lane = t & 63;
    const int quad = lane >> 4, l16 = lane & 15;

    // XCD-aware: XCD x owns images [16x,16x+16); image-fast, caption-group-slow.
    const int lin = blockIdx.x;           // 0..4095
    const int xcd = lin & 7, k = lin >> 3; // k 0..511
    const int ii = k & 15, jg = k >> 4;    // 16 images x 32 caption-groups per XCD
    const int i = xcd * 16 + ii;
    const int j = jg * 4 + wave;           // this wave's caption
    const int L = s_l[j];

    const f16* Ab = im16 + (size_t)i * (MT * ND);
    const f16* Bb = s16 + (size_t)j * (NW * ND);
    const int fo = l16 * ND + quad * 8;    // + tile*16*ND + kk

    f32x4 acc[3][4];
    #pragma unroll
    for (int mi = 0; mi < 3; ++mi)
        #pragma unroll
        for (int nt = 0; nt < 4; ++nt)
            acc[mi][nt] = (f32x4){0.f, 0.f, 0.f, 0.f};

    // ---- K-loop: pure global(L2) loads + MFMA; A shared by all 4 waves (L1) ----
    for (int kk = 0; kk < ND; kk += 32) {
        f16x8 bfr[4], ar[3];
        #pragma unroll
        for (int nt = 0; nt < 4; ++nt)
            bfr[nt] = *(const f16x8*)(Bb + nt * 16 * ND + fo + kk);
        #pragma unroll
        for (int mi = 0; mi < 3; ++mi)
            ar[mi] = *(const f16x8*)(Ab + mi * 16 * ND + fo + kk);
        #pragma unroll
        for (int mi = 0; mi < 3; ++mi)
            #pragma unroll
            for (int nt = 0; nt < 4; ++nt)
                acc[mi][nt] = __builtin_amdgcn_mfma_f32_16x16x32_f16(ar[mi], bfr[nt], acc[mi][nt], 0, 0, 0);
    }

    // ---- wave-private epilogue ----
    char* waveE = smemE + wave * 8192;
    {   // zero E^T rows 48..63 (chunks 6,7): NaN guard vs 0xAA poison in quadform
        f16x8 z = {(f16)0.f, (f16)0.f, (f16)0.f, (f16)0.f, (f16)0.f, (f16)0.f, (f16)0.f, (f16)0.f};
        int col = lane;
        *(f16x8*)(waveE + col * 128 + ((6 ^ (col & 7)) * 16)) = z;
        *(f16x8*)(waveE + col * 128 + ((7 ^ (col & 7)) * 16)) = z;
    }

    // -- per-row l2-norm reciprocal (rows >= 36 -> 0) --
    float rn[3][4];
    #pragma unroll
    for (int mi = 0; mi < 3; ++mi) {
        #pragma unroll
        for (int r = 0; r < 4; ++r) {
            int row = mi * 16 + quad * 4 + r;
            float ss = 0.f;
            #pragma unroll
            for (int nt = 0; nt < 4; ++nt) {
                int col = nt * 16 + l16;
                float v = acc[mi][nt][r];
                float lv = v > 0.f ? v : 0.1f * v;
                if (col < L) ss += lv * lv;
            }
            ss += __shfl_xor(ss, 1, 64);
            ss += __shfl_xor(ss, 2, 64);
            ss += __shfl_xor(ss, 4, 64);
            ss += __shfl_xor(ss, 8, 64);
            rn[mi][r] = (row < NR) ? 1.0f / (sqrtf(ss) + EPSF) : 0.f;
        }
    }
    // -- e = exp(9*an): write E^T f16 (swizzled); cs/nu per-col partials --
    float cs[4] = {0.f, 0.f, 0.f, 0.f}, nu[4] = {0.f, 0.f, 0.f, 0.f};
    #pragma unroll
    for (int mi = 0; mi < 3; ++mi) {
        #pragma unroll
        for (int nt = 0; nt < 4; ++nt) {
            int col = nt * 16 + l16;
            f16x4 ew;
            #pragma unroll
            for (int r = 0; r < 4; ++r) {
                float v = acc[mi][nt][r];
                float lv = v > 0.f ? v : 0.1f * v;
                float e = expf(LAM_SM * ((col < L) ? lv * rn[mi][r] : 0.f));
                ew[r] = (f16)e;
                if (mi * 16 + quad * 4 + r < NR) { cs[nt] += e; nu[nt] += e * v; }
            }
            int c = mi * 2 + (quad >> 1);
            *(f16x4*)(waveE + col * 128 + ((c ^ (col & 7)) * 16) + (quad & 1) * 8) = ew;
        }
    }
    #pragma unroll
    for (int nt = 0; nt < 4; ++nt) {
        cs[nt] += __shfl_xor(cs[nt], 16, 64); cs[nt] += __shfl_xor(cs[nt], 32, 64);
        nu[nt] += __shfl_xor(nu[nt], 16, 64); nu[nt] += __shfl_xor(nu[nt], 32, 64);
    }
    // acc is dead here -> register pressure drops before quadform.

    // -- quadform mi-at-a-time: y (16 regs) = M[mi,:] x E^T; qf += e . y --
    const f16* Mi = Mg16 + (size_t)i * (MT * NW);
    float qf[4] = {0.f, 0.f, 0.f, 0.f};
    #pragma unroll
    for (int mi = 0; mi < 3; ++mi) {
        f32x4 y[4];
        #pragma unroll
        for (int nt = 0; nt < 4; ++nt) y[nt] = (f32x4){0.f, 0.f, 0.f, 0.f};
        #pragma unroll
        for (int ks = 0; ks < 2; ++ks) {
            f16x8 aq = *(const f16x8*)(Mi + (mi * 16 + l16) * NW + ks * 32 + quad * 8);
            #pragma unroll
            for (int nt = 0; nt < 4; ++nt) {
                int col = nt * 16 + l16;
                int pch = (ks * 4 + quad) ^ (col & 7);
                f16x8 bq = *(const f16x8*)(waveE + col * 128 + pch * 16);
                y[nt] = __builtin_amdgcn_mfma_f32_16x16x32_f16(aq, bq, y[nt], 0, 0, 0);
            }
        }
        int row0 = mi * 16 + quad * 4;
        int c = row0 >> 3, sub = (row0 >> 2) & 1;
        #pragma unroll
        for (int nt = 0; nt < 4; ++nt) {
            int col = nt * 16 + l16;
            f16x4 ev = *(const f16x4*)(waveE + col * 128 + ((c ^ (col & 7)) * 16) + sub * 8);
            #pragma unroll
            for (int r = 0; r < 4; ++r) qf[nt] += y[nt][r] * (float)ev[r];
        }
    }
    #pragma unroll
    for (int nt = 0; nt < 4; ++nt) {
        qf[nt] += __shfl_xor(qf[nt], 16, 64); qf[nt] += __shfl_xor(qf[nt], 32, 64);
    }
    // -- finalize: cosine row values, LSE over words, write score --
    float lse = 0.f;
    #pragma unroll
    for (int nt = 0; nt < 4; ++nt) {
        int col = nt * 16 + l16;
        float num  = nu[nt] / cs[nt];
        float nwei = sqrtf(fmaxf(qf[nt], 0.f)) / cs[nt];
        float nc   = ncap[j * NW + col];
        float rowv = num / fmaxf(nc * nwei, EPSF);
        lse += (col < L) ? expf(LAM_LSE * rowv) : 0.f;
    }
    lse += __shfl_xor(lse, 1, 64);
    lse += __shfl_xor(lse, 2, 64);
    lse += __shfl_xor(lse, 4, 64);
    lse += __shfl_xor(lse, 8, 64);
    if (lane == 0) scores[i * NB + j] = logf(lse) / LAM_LSE;
}

// ---------------- kernel C: contrastive loss reduction ----------------
__global__ __launch_bounds__(128) void loss_kernel(const float* __restrict__ S,
                                                   float* __restrict__ out) {
    __shared__ float part[NB];
    int t = threadIdx.x;
    float dii = S[t * NB + t];
    float rmax = 0.f, cmax = 0.f;
    for (int k = 0; k < NB; ++k) {
        if (k != t) {
            float vs = MARGINF + S[t * NB + k] - dii;
            rmax = fmaxf(rmax, fmaxf(vs, 0.f));
            float vi = MARGINF + S[k * NB + t] - dii;
            cmax = fmaxf(cmax, fmaxf(vi, 0.f));
        }
    }
    part[t] = rmax + cmax;
    __syncthreads();
    if (t == 0) {
        float sum = 0.f;
        for (int k = 0; k < NB; ++k) sum += part[k];
        out[0] = sum;
    }
}

extern "C" void kernel_launch(void* const* d_in, const int* in_sizes, int n_in,
                              void* d_out, int out_size, void* d_ws, size_t ws_size,
                              hipStream_t stream) {
    const float* im  = (const float*)d_in[0];
    const float* s   = (const float*)d_in[1];
    const int*   s_l = (const int*)d_in[2];

    float* scores = (float*)d_ws;                          // 16384 f
    float* ncap   = scores + NB * NB;                      // 8192 f
    f16*   Mg16   = (f16*)(ncap + NB * NW);                // 128*48*64 f16
    f16*   im16   = Mg16 + (size_t)NB * MT * NW;           // 128*48*1024 f16
    f16*   s16    = im16 + (size_t)NB * MT * ND;           // 128*64*1024 f16

    dim3 cgrid(NB, MT + NW);
    convert_kernel<<<cgrid, 256, 0, stream>>>(im, s, im16, s16, ncap);
    dim3 ggrid(NB, 3);
    gram16_kernel<<<ggrid, 256, 0, stream>>>(im16, Mg16);
    pair_mfma_kernel<<<4096, 256, 0, stream>>>(im16, s16, s_l, Mg16, ncap, scores);
    loss_kernel<<<1, NB, 0, stream>>>(scores, (float*)d_out);
}

// Round 6
// 312.235 us; speedup vs baseline: 1.7920x; 1.7920x over previous
//
#include <hip/hip_runtime.h>
#include <hip/hip_bf16.h>
#include <math.h>
#include <stdint.h>

#define NB 128     // batch (images and captions)
#define NR 36      // regions
#define NW 64      // words
#define ND 1024    // dim
#define MT 48      // NR padded for Gram tiles
#define EPSF 1e-8f
#define LAM_SM 9.0f
#define LAM_LSE 6.0f
#define MARGINF 0.2f

typedef _Float16 f16;
typedef f16 f16x4 __attribute__((ext_vector_type(4)));
typedef f16 f16x8 __attribute__((ext_vector_type(8)));
typedef float f32x4 __attribute__((ext_vector_type(4)));

__device__ __forceinline__ void gld_lds16(const void* g, void* l) {
    __builtin_amdgcn_global_load_lds(
        (const __attribute__((address_space(1))) uint32_t*)(uintptr_t)g,
        (__attribute__((address_space(3))) uint32_t*)(uint32_t)(uintptr_t)l,
        16, 0, 0);
}

// ---------------- kernel 0: fp32 -> f16 packed (36 rows/img, 64 rows/cap) + ncap --
__global__ __launch_bounds__(256) void convert_kernel(
    const float* __restrict__ im, const float* __restrict__ s,
    f16* __restrict__ im36, f16* __restrict__ s16, float* __restrict__ ncap) {
    __shared__ float wsum[4];
    const int b = blockIdx.x, row = blockIdx.y, t = threadIdx.x;
    if (row < NR) {
        const float4* src = (const float4*)(im + ((size_t)b * NR + row) * ND);
        float4 v = src[t];
        f16x4 h = {(f16)v.x, (f16)v.y, (f16)v.z, (f16)v.w};
        ((f16x4*)(im36 + ((size_t)b * NR + row) * ND))[t] = h;
    } else {
        const int w = row - NR;
        const float4* src = (const float4*)(s + ((size_t)b * NW + w) * ND);
        float4 v = src[t];
        f16x4 h = {(f16)v.x, (f16)v.y, (f16)v.z, (f16)v.w};
        ((f16x4*)(s16 + ((size_t)b * NW + w) * ND))[t] = h;
        float ss = v.x * v.x + v.y * v.y + v.z * v.z + v.w * v.w;
        #pragma unroll
        for (int off = 1; off < 64; off <<= 1) ss += __shfl_xor(ss, off, 64);
        if ((t & 63) == 0) wsum[t >> 6] = ss;
        __syncthreads();
        if (t == 0) ncap[b * NW + w] = sqrtf(wsum[0] + wsum[1] + wsum[2] + wsum[3]);
    }
}

// ---------------- kernel A: per-image f16 Gram [48][64] via MFMA (pad rows -> 0) --
__global__ __launch_bounds__(256) void gram16_kernel(
    const f16* __restrict__ im36, f16* __restrict__ Mg16) {
    const int b = blockIdx.x, mt = blockIdx.y;          // mt 0..2
    const int wave = threadIdx.x >> 6, lane = threadIdx.x & 63;
    const int quad = lane >> 4, l16 = lane & 15;
    const int nt = wave;                                 // n-tile 0..3
    const f16* Ab = im36 + (size_t)b * (NR * ND);
    const int ra = mt * 16 + l16, rb = nt * 16 + l16;
    const f16x8 z8 = {(f16)0.f,(f16)0.f,(f16)0.f,(f16)0.f,(f16)0.f,(f16)0.f,(f16)0.f,(f16)0.f};
    f32x4 acc = (f32x4){0.f, 0.f, 0.f, 0.f};
    for (int kk = 0; kk < ND; kk += 32) {
        f16x8 af = (ra < NR) ? *(const f16x8*)(Ab + ra * ND + kk + quad * 8) : z8;
        f16x8 bf = (rb < NR) ? *(const f16x8*)(Ab + rb * ND + kk + quad * 8) : z8;
        acc = __builtin_amdgcn_mfma_f32_16x16x32_f16(af, bf, acc, 0, 0, 0);
    }
    f16* Mb = Mg16 + (size_t)b * (MT * NW);
    #pragma unroll
    for (int r = 0; r < 4; ++r) {
        int row = mt * 16 + quad * 4 + r;
        Mb[row * NW + nt * 16 + l16] = (f16)acc[r];
    }
}

// ---------------- kernel B1: big GEMM Craw = im36 x s16^T (m97 structure) ---------
// M=4608 (128 img x 36 r), N=8192 (128 cap x 64 w), K=1024. 128x128 tiles, BK=64.
// LDS rows are 128 B (row stride == 0 mod 32 banks) so chunk XOR-swizzle is exact.
// C stored f16 in per-pair tile layout: Craw[(i*128+j)*2304 + r*64 + w].
__global__ __launch_bounds__(256) void gemm_craw_kernel(
    const f16* __restrict__ A, const f16* __restrict__ B, f16* __restrict__ Craw) {
    __shared__ __align__(16) char lds[32768];
    char* As = lds;            // [128 rows][128 B]
    char* Bs = lds + 16384;
    const int t = threadIdx.x;
    const int wave = t >> 6, lane = t & 63;
    const int quad = lane >> 4, l16 = lane & 15;
    const int wm = wave >> 1, wn = wave & 1;
    // panel mapping: 8 gx per panel, gy fast -> B-panel (2MB) stays L2-hot
    const int lin = blockIdx.x;               // 0..2303
    const int p = lin / 288, w8 = lin % 288;
    const int gy = w8 % 36, gx = p * 8 + w8 / 36;
    const f16* Ab = A + (size_t)gy * 128 * ND;
    const f16* Bb = B + (size_t)gx * 128 * ND;

    // staging: 4 issues per tile; issue q covers bytes [q*4096, q*4096+4096)
    int srow[4], soff[4];
    #pragma unroll
    for (int q = 0; q < 4; ++q) {
        int f = q * 4096 + t * 16;
        int row = f >> 7, c = (f >> 4) & 7;
        int sc = c ^ (row & 7);
        srow[q] = row; soff[q] = row * ND + sc * 8;
    }

    f32x4 acc[4][4];
    #pragma unroll
    for (int mt = 0; mt < 4; ++mt)
        #pragma unroll
        for (int nt = 0; nt < 4; ++nt)
            acc[mt][nt] = (f32x4){0.f, 0.f, 0.f, 0.f};

    for (int kk = 0; kk < ND; kk += 64) {
        #pragma unroll
        for (int q = 0; q < 4; ++q)
            gld_lds16(Ab + soff[q] + kk, As + q * 4096 + t * 16);
        #pragma unroll
        for (int q = 0; q < 4; ++q)
            gld_lds16(Bb + soff[q] + kk, Bs + q * 4096 + t * 16);
        __syncthreads();
        #pragma unroll
        for (int ks = 0; ks < 2; ++ks) {
            f16x8 af[4], bf[4];
            #pragma unroll
            for (int mt = 0; mt < 4; ++mt) {
                int row = wm * 64 + mt * 16 + l16;
                int pc = (ks * 4 + quad) ^ (row & 7);
                af[mt] = *(const f16x8*)(As + row * 128 + pc * 16);
            }
            #pragma unroll
            for (int nt = 0; nt < 4; ++nt) {
                int row = wn * 64 + nt * 16 + l16;
                int pc = (ks * 4 + quad) ^ (row & 7);
                bf[nt] = *(const f16x8*)(Bs + row * 128 + pc * 16);
            }
            #pragma unroll
            for (int mt = 0; mt < 4; ++mt)
                #pragma unroll
                for (int nt = 0; nt < 4; ++nt)
                    acc[mt][nt] = __builtin_amdgcn_mfma_f32_16x16x32_f16(af[mt], bf[nt], acc[mt][nt], 0, 0, 0);
        }
        __syncthreads();
    }

    // epilogue: f16 store into per-pair tile layout (C-layout: row=quad*4+r, col=l16)
    #pragma unroll
    for (int mt = 0; mt < 4; ++mt) {
        const int R = gy * 128 + wm * 64 + mt * 16 + quad * 4;   // +r
        #pragma unroll
        for (int r = 0; r < 4; ++r) {
            const int Rr = R + r;
            const int i = Rr / 36, r36 = Rr - i * 36;
            #pragma unroll
            for (int nt = 0; nt < 4; ++nt) {
                const int C = gx * 128 + wn * 64 + nt * 16 + l16;
                const int j = C >> 6, wd = C & 63;
                Craw[((size_t)(i * NB + j)) * (NR * NW) + r36 * NW + wd] = (f16)acc[mt][nt][r];
            }
        }
    }
}

// ---------------- kernel B2: per-pair epilogue (block = 1 pair) -------------------
// LDS: Araw f32[36][65] + eT16 (64 cols x 128B, XOR-swizzled) + rnorm[48] + contribS[64]
__global__ __launch_bounds__(256) void pair_epilogue_kernel(
    const f16* __restrict__ Craw, const int* __restrict__ s_l,
    const f16* __restrict__ Mg16, const float* __restrict__ ncap,
    float* __restrict__ scores) {
    __shared__ __align__(16) float Araw[NR * 65];
    __shared__ __align__(16) char eT16[64 * 128];
    __shared__ float rnorm[48];
    __shared__ float contribS[64];
    const int j = blockIdx.x, i = blockIdx.y;
    const int t = threadIdx.x;
    const int wave = t >> 6, lane = t & 63;
    const int quad = lane >> 4, l16 = lane & 15;
    const int col = wave * 16 + l16;
    const int L = s_l[j];

    // ---- load contiguous pair tile (4608 B) into Araw ----
    const f16* tile = Craw + ((size_t)(i * NB + j)) * (NR * NW);
    for (int c = t; c < (NR * NW) / 8; c += 256) {          // 288 chunks of f16x8
        f16x8 v = ((const f16x8*)tile)[c];
        int r = c >> 3, w0 = (c & 7) * 8;
        #pragma unroll
        for (int k = 0; k < 8; ++k) Araw[r * 65 + w0 + k] = (float)v[k];
    }
    {   // zero eT16 rows 48..63 (chunks 6,7): pad guard for quadform
        f16x8 z = {(f16)0.f,(f16)0.f,(f16)0.f,(f16)0.f,(f16)0.f,(f16)0.f,(f16)0.f,(f16)0.f};
        int wz = lane, row0 = 48 + wave * 4;
        int c = row0 >> 3, sub = (row0 >> 2) & 1;
        *(f16x4*)(eT16 + wz * 128 + ((c ^ (wz & 7)) * 16) + sub * 8) =
            (f16x4){(f16)0.f,(f16)0.f,(f16)0.f,(f16)0.f};
        (void)z;
    }
    __syncthreads();

    // ---- per-row l2 norm over masked, leaky words ----
    if (t < 144) {
        int r = t >> 2, q = t & 3;
        float ss = 0.f;
        for (int k = 0; k < 16; ++k) {
            int w = q * 16 + k;
            float v = Araw[r * 65 + w];
            float lv = v > 0.f ? v : 0.1f * v;
            if (w < L) ss += lv * lv;
        }
        ss += __shfl_xor(ss, 1, 64);
        ss += __shfl_xor(ss, 2, 64);
        if (q == 0) rnorm[r] = 1.0f / (sqrtf(ss) + EPSF);
    } else if (t < 156) {
        rnorm[t - 108] = 0.f;   // rows 36..47
    }
    __syncthreads();

    // ---- e = exp(9*an); write E^T f16 swizzled; cs/nu partials (own column) ----
    float cs = 0.f, nu = 0.f;
    #pragma unroll
    for (int mi = 0; mi < 3; ++mi) {
        f16x4 ew;
        #pragma unroll
        for (int r = 0; r < 4; ++r) {
            int row = mi * 16 + quad * 4 + r;
            float v = (row < NR) ? Araw[row * 65 + col] : 0.f;
            float lv = v > 0.f ? v : 0.1f * v;
            float an = (col < L) ? lv * rnorm[row] : 0.f;
            float e = expf(LAM_SM * an);
            ew[r] = (f16)e;
            if (row < NR) { cs += e; nu += e * v; }
        }
        int c = mi * 2 + (quad >> 1);
        *(f16x4*)(eT16 + col * 128 + ((c ^ (col & 7)) * 16) + (quad & 1) * 8) = ew;
    }
    cs += __shfl_xor(cs, 16, 64); cs += __shfl_xor(cs, 32, 64);
    nu += __shfl_xor(nu, 16, 64); nu += __shfl_xor(nu, 32, 64);
    __syncthreads();

    // ---- quadform via MFMA: y = M (global L2) x E^T (LDS); qf = e . y ----
    const f16* Mi = Mg16 + (size_t)i * (MT * NW);
    float qf = 0.f;
    #pragma unroll
    for (int mi = 0; mi < 3; ++mi) {
        f32x4 y = (f32x4){0.f, 0.f, 0.f, 0.f};
        #pragma unroll
        for (int ks = 0; ks < 2; ++ks) {
            f16x8 aq = *(const f16x8*)(Mi + (mi * 16 + l16) * NW + ks * 32 + quad * 8);
            int pch = (ks * 4 + quad) ^ (col & 7);
            f16x8 bq = *(const f16x8*)(eT16 + col * 128 + pch * 16);
            y = __builtin_amdgcn_mfma_f32_16x16x32_f16(aq, bq, y, 0, 0, 0);
        }
        int row0 = mi * 16 + quad * 4;
        int c = row0 >> 3, sub = (row0 >> 2) & 1;
        f16x4 ev = *(const f16x4*)(eT16 + col * 128 + ((c ^ (col & 7)) * 16) + sub * 8);
        #pragma unroll
        for (int r = 0; r < 4; ++r) qf += y[r] * (float)ev[r];
    }
    qf += __shfl_xor(qf, 16, 64); qf += __shfl_xor(qf, 32, 64);

    if (quad == 0) {
        float num  = nu / cs;
        float nwei = sqrtf(fmaxf(qf, 0.f)) / cs;
        float nc   = ncap[j * NW + col];
        float rowv = num / fmaxf(nc * nwei, EPSF);
        contribS[col] = (col < L) ? expf(LAM_LSE * rowv) : 0.f;
    }
    __syncthreads();

    if (t < 64) {
        float contrib = contribS[t];
        #pragma unroll
        for (int off = 32; off; off >>= 1) contrib += __shfl_xor(contrib, off, 64);
        if (t == 0) scores[i * NB + j] = logf(contrib) / LAM_LSE;
    }
}

// ---------------- kernel C: contrastive loss reduction ----------------
__global__ __launch_bounds__(128) void loss_kernel(const float* __restrict__ S,
                                                   float* __restrict__ out) {
    __shared__ float part[NB];
    int t = threadIdx.x;
    float dii = S[t * NB + t];
    float rmax = 0.f, cmax = 0.f;
    for (int k = 0; k < NB; ++k) {
        if (k != t) {
            float vs = MARGINF + S[t * NB + k] - dii;
            rmax = fmaxf(rmax, fmaxf(vs, 0.f));
            float vi = MARGINF + S[k * NB + t] - dii;
            cmax = fmaxf(cmax, fmaxf(vi, 0.f));
        }
    }
    part[t] = rmax + cmax;
    __syncthreads();
    if (t == 0) {
        float sum = 0.f;
        for (int k = 0; k < NB; ++k) sum += part[k];
        out[0] = sum;
    }
}

extern "C" void kernel_launch(void* const* d_in, const int* in_sizes, int n_in,
                              void* d_out, int out_size, void* d_ws, size_t ws_size,
                              hipStream_t stream) {
    const float* im  = (const float*)d_in[0];
    const float* s   = (const float*)d_in[1];
    const int*   s_l = (const int*)d_in[2];

    float* scores = (float*)d_ws;                          // 16384 f32
    float* ncap   = scores + NB * NB;                      // 8192 f32
    f16*   Mg16   = (f16*)(ncap + NB * NW);                // 128*48*64
    f16*   im36   = Mg16 + (size_t)NB * MT * NW;           // 128*36*1024
    f16*   s16    = im36 + (size_t)NB * NR * ND;           // 128*64*1024
    f16*   Craw   = s16 + (size_t)NB * NW * ND;            // 4608*8192 (~72 MB)

    dim3 cgrid(NB, NR + NW);
    convert_kernel<<<cgrid, 256, 0, stream>>>(im, s, im36, s16, ncap);
    dim3 ggrid(NB, 3);
    gram16_kernel<<<ggrid, 256, 0, stream>>>(im36, Mg16);
    gemm_craw_kernel<<<2304, 256, 0, stream>>>(im36, s16, Craw);
    dim3 egrid(NB, NB);
    pair_epilogue_kernel<<<egrid, 256, 0, stream>>>(Craw, s_l, Mg16, ncap, scores);
    loss_kernel<<<1, NB, 0, stream>>>(scores, (float*)d_out);
}